// Round 1
// baseline (1032.962 us; speedup 1.0000x reference)
//
#include <hip/hip_runtime.h>

// Problem constants (match reference)
#define BB 2048
#define HH 50
#define DD 400
#define SS 285
#define CC 18
#define NCC 50
#define FILLV 1e-30f

static constexpr int BLOCK = 512;

// Output offsets (elements)
static constexpr size_t OFF1 = (size_t)BB * SS * DD;            // sub_weights
static constexpr size_t OFF2 = OFF1 + (size_t)BB * SS;          // cat_repr
static constexpr size_t OFF3 = OFF2 + (size_t)BB * CC * DD;     // cat_weights
static constexpr size_t OFF4 = OFF3 + (size_t)BB * CC;          // user_repr

__global__ __launch_bounds__(BLOCK, 1) void hierec_fused(
    const float* __restrict__ vectors,      // [B,H,D]
    const int*   __restrict__ subcategory,  // [B,H]
    const int*   __restrict__ category,     // [B,H]
    const float* __restrict__ subcat_embed, // [S,D]
    const float* __restrict__ cat_embed,    // [C,D]
    const float* __restrict__ clicks_embed, // [H,NC]
    const float* __restrict__ w_news,       // [D]
    const float* __restrict__ w_subcat,     // [D+NC]
    const float* __restrict__ w_cat,        // [D+NC]
    float* __restrict__ out)
{
    const int b    = blockIdx.x;
    const int tid  = threadIdx.x;
    const int lane = tid & 63;
    const int wave = tid >> 6;

    __shared__ float catbuf[CC][DD];     // 28800 B
    __shared__ float vtotL[DD];
    __shared__ float sceL[SS];
    __shared__ int   s_first[SS];
    __shared__ float ns1L[HH], ns2L[HH], eL[HH], uL[HH], ZL[HH], scL[HH];
    __shared__ unsigned long long maskL[HH];
    __shared__ int   hsL[HH], hcL[HH], cntL[HH], repL[HH], prepL[HH];
    __shared__ float cedsL[HH], cedcL[HH];
    __shared__ float mcL[CC], ucL[CC], ZcL[CC], csL[CC], catwL[CC];
    __shared__ int   ncL[CC], cntcL[CC];
    __shared__ int   ndL;

    const float* vb = vectors + (size_t)b * HH * DD;

    // ---------------- P0: load click ids, init s_first ----------------
    if (tid < HH) {
        hsL[tid] = subcategory[b * HH + tid];
        hcL[tid] = category[b * HH + tid];
    }
    for (int s = tid; s < SS; s += BLOCK) s_first[s] = -1;
    __syncthreads();

    // ---------------- P1: per-row dots + vtot ----------------
    // ns1[h] = v_h . w_news ;  ns2[h] = v_h . w_subcat[:D]
    for (int h = wave; h < HH; h += 8) {
        float p1 = 0.f, p2 = 0.f;
        for (int d = lane; d < DD; d += 64) {
            float v = vb[h * DD + d];
            p1 += v * w_news[d];
            p2 += v * w_subcat[d];
        }
        for (int off = 32; off; off >>= 1) {
            p1 += __shfl_down(p1, off);
            p2 += __shfl_down(p2, off);
        }
        if (lane == 0) { ns1L[h] = p1; ns2L[h] = p2; }
    }
    // sce[s] = subcat_embed[s] . w_subcat[:D]
    for (int s = wave; s < SS; s += 8) {
        float p = 0.f;
        for (int d = lane; d < DD; d += 64) p += subcat_embed[s * DD + d] * w_subcat[d];
        for (int off = 32; off; off >>= 1) p += __shfl_down(p, off);
        if (lane == 0) sceL[s] = p;
    }
    // ced_sub[k] = clicks_embed[k] . w_subcat[D:] ; ced_cat similarly
    for (int k = wave; k < HH; k += 8) {
        float p1 = 0.f, p2 = 0.f;
        if (lane < NCC) {
            float v = clicks_embed[k * NCC + lane];
            p1 = v * w_subcat[DD + lane];
            p2 = v * w_cat[DD + lane];
        }
        for (int off = 32; off; off >>= 1) {
            p1 += __shfl_down(p1, off);
            p2 += __shfl_down(p2, off);
        }
        if (lane == 0) { cedsL[k] = p1; cedcL[k] = p2; }
    }
    // vtot[d] = sum_h v[h][d]
    if (tid < DD) {
        float a = 0.f;
        for (int h = 0; h < HH; ++h) a += vb[h * DD + tid];
        vtotL[tid] = a;
    }
    __syncthreads();

    // ---------------- P2: per-click (per-h) softmax stats ----------------
    if (tid < HH) {
        const int h = tid;
        const int s = hsL[h], c = hcL[h];
        unsigned long long mask = 0ull, pmask = 0ull;
        for (int j = 0; j < HH; ++j) {
            bool ms = (hsL[j] == s);
            mask  |= (unsigned long long)(ms ? 1 : 0) << j;
            pmask |= (unsigned long long)((ms && hcL[j] == c) ? 1 : 0) << j;
        }
        int cnt = __popcll(mask);
        int first = __ffsll((long long)mask) - 1;
        bool rep = (first == h);

        float m = FILLV;
        unsigned long long t = mask;
        while (t) { int j = __ffsll((long long)t) - 1; t &= t - 1; m = fmaxf(m, ns1L[j]); }
        float u = expf(FILLV - m);
        float sumE = 0.f, sum2 = 0.f;
        t = mask;
        while (t) {
            int j = __ffsll((long long)t) - 1; t &= t - 1;
            float e = expf(ns1L[j] - m);
            sumE += e;
            sum2 += (e - u) * ns2L[j];
        }
        float Z = sumE + (float)(HH - cnt) * u;
        float vt2 = 0.f;
        for (int j = 0; j < HH; ++j) vt2 += ns2L[j];
        int ci = cnt < (NCC - 1) ? cnt : (NCC - 1);
        float sc = (sum2 + u * vt2) / Z + sceL[s] + cedsL[ci];

        eL[h] = expf(ns1L[h] - m);
        uL[h] = u; ZL[h] = Z; cntL[h] = cnt; maskL[h] = mask; scL[h] = sc;
        repL[h] = rep ? 1 : 0;
        prepL[h] = ((__ffsll((long long)pmask) - 1) == h) ? 1 : 0;
        if (rep) s_first[s] = h;
    }
    __syncthreads();

    // ---------------- P3: per-category stats + sub_weights out ----------------
    if (tid < CC) {
        const int c = tid;
        float mc = FILLV; int n = 0, cc2 = 0;
        for (int j = 0; j < HH; ++j) {
            if (hcL[j] == c) ++cc2;
            if (prepL[j] && hcL[j] == c) { ++n; mc = fmaxf(mc, scL[j]); }
        }
        float u = expf(FILLV - mc);
        float sumE = 0.f;
        for (int j = 0; j < HH; ++j)
            if (prepL[j] && hcL[j] == c) sumE += expf(scL[j] - mc);
        ZcL[c] = sumE + (float)(SS - n) * u;
        mcL[c] = mc; ucL[c] = u; ncL[c] = n; cntcL[c] = cc2;
    }
    if (tid == CC) {
        int nd = 0;
        for (int j = 0; j < HH; ++j) nd += repL[j];
        ndL = nd;
    }
    if (tid < SS) {
        int f = s_first[tid];
        float w = (f >= 0) ? (float)cntL[f] / (float)HH : 0.f;
        out[OFF1 + (size_t)b * SS + tid] = w;
    }
    __syncthreads();

    // ---------------- P4: write sub_repr (the big one) ----------------
    float etot = 0.f;
    if (tid < DD) {
        const int d = tid;
        const float vt = vtotL[d];
        for (int s = 0; s < SS; ++s) {
            float embv = subcat_embed[s * DD + d];
            etot += embv;
            int f = s_first[s];
            float val;
            if (f < 0) {
                val = vt * (1.f / (float)HH) + embv;
            } else {
                float u = uL[f], Z = ZL[f];
                float acc = u * vt;
                unsigned long long t = maskL[f];
                while (t) {
                    int j = __ffsll((long long)t) - 1; t &= t - 1;
                    acc += (eL[j] - u) * vb[j * DD + d];
                }
                val = acc / Z + embv;
            }
            out[((size_t)(b * SS + s)) * DD + d] = val;
        }
    }

    // ---------------- P5: cat_repr ----------------
    if (tid < DD) {
        const int d = tid;
        const float vt = vtotL[d];
        float rtot = (float)(SS - ndL) * vt * (1.f / (float)HH) + etot;
        // add snr of each distinct clicked s
        for (int j = 0; j < HH; ++j) {
            if (repL[j]) {
                float u = uL[j], Z = ZL[j];
                float acc = u * vt;
                unsigned long long t = maskL[j];
                while (t) {
                    int k = __ffsll((long long)t) - 1; t &= t - 1;
                    acc += (eL[k] - u) * vb[k * DD + d];
                }
                rtot += acc / Z;
            }
        }
        for (int c = 0; c < CC; ++c) catbuf[c][d] = ucL[c] * rtot;
        for (int j = 0; j < HH; ++j) {
            if (prepL[j]) {
                int c = hcL[j];
                float uc = ucL[c];
                float e = expf(scL[j] - mcL[c]);
                float u = uL[j], Z = ZL[j];
                float acc = u * vt;
                unsigned long long t = maskL[j];
                while (t) {
                    int k = __ffsll((long long)t) - 1; t &= t - 1;
                    acc += (eL[k] - u) * vb[k * DD + d];
                }
                float subr = acc / Z + subcat_embed[hsL[j] * DD + d];
                catbuf[c][d] += (e - uc) * subr;
            }
        }
        for (int c = 0; c < CC; ++c) {
            float val = catbuf[c][d] / ZcL[c] + cat_embed[c * DD + d];
            catbuf[c][d] = val;
            out[OFF2 + ((size_t)(b * CC + c)) * DD + d] = val;
        }
    }
    if (tid < CC) out[OFF3 + (size_t)b * CC + tid] = (float)cntcL[tid] / (float)HH;
    __syncthreads();

    // ---------------- P6: c_scores ----------------
    for (int c = wave; c < CC; c += 8) {
        float p = 0.f;
        for (int d = lane; d < DD; d += 64) p += catbuf[c][d] * w_cat[d];
        for (int off = 32; off; off >>= 1) p += __shfl_down(p, off);
        if (lane == 0) {
            int ci = cntcL[c] < (NCC - 1) ? cntcL[c] : (NCC - 1);
            csL[c] = p + cedcL[ci];
        }
    }
    __syncthreads();

    // ---------------- P7: softmax over C + user_repr ----------------
    if (tid < CC) {
        float m = csL[0];
        for (int j = 1; j < CC; ++j) m = fmaxf(m, csL[j]);
        float Zc = 0.f;
        for (int j = 0; j < CC; ++j) Zc += expf(csL[j] - m);
        catwL[tid] = expf(csL[tid] - m) / Zc;
    }
    __syncthreads();
    if (tid < DD) {
        float a = 0.f;
        for (int c = 0; c < CC; ++c) a += catwL[c] * catbuf[c][tid];
        out[OFF4 + (size_t)b * DD + tid] = a;
    }
}

extern "C" void kernel_launch(void* const* d_in, const int* in_sizes, int n_in,
                              void* d_out, int out_size, void* d_ws, size_t ws_size,
                              hipStream_t stream) {
    const float* vectors      = (const float*)d_in[0];
    const int*   subcategory  = (const int*)d_in[1];
    const int*   category     = (const int*)d_in[2];
    const float* subcat_embed = (const float*)d_in[3];
    const float* cat_embed    = (const float*)d_in[4];
    const float* clicks_embed = (const float*)d_in[5];
    const float* w_news       = (const float*)d_in[6];
    const float* w_subcat     = (const float*)d_in[7];
    const float* w_cat        = (const float*)d_in[8];
    float* out = (float*)d_out;

    hipLaunchKernelGGL(hierec_fused, dim3(BB), dim3(BLOCK), 0, stream,
                       vectors, subcategory, category, subcat_embed, cat_embed,
                       clicks_embed, w_news, w_subcat, w_cat, out);
}

// Round 2
// 592.832 us; speedup vs baseline: 1.7424x; 1.7424x over previous
//
#include <hip/hip_runtime.h>

// Problem constants (match reference)
#define BB 2048
#define HH 50
#define DD 400
#define D4 100            // DD/4 float4 per row
#define SS 285
#define CC 18
#define NCC 50
#define FILLV 1e-30f

static constexpr int BLOCK = 512;
static constexpr int TOT4 = SS * D4;   // 28500 float4 elements of sub_repr per batch

// Output offsets (elements)
static constexpr size_t OFF1 = (size_t)BB * SS * DD;            // sub_weights
static constexpr size_t OFF2 = OFF1 + (size_t)BB * SS;          // cat_repr
static constexpr size_t OFF3 = OFF2 + (size_t)BB * CC * DD;     // cat_weights
static constexpr size_t OFF4 = OFF3 + (size_t)BB * CC;          // user_repr

// d_ws layout (floats): [0..399] etot  [400..684] sce  [685..734] ced_sub  [735..784] ced_cat
#define WS_ETOT 0
#define WS_SCE  400
#define WS_CEDS 685
#define WS_CEDC 735

__device__ __forceinline__ float4 f4fma(float a, float4 b, float4 c) {
    return make_float4(fmaf(a, b.x, c.x), fmaf(a, b.y, c.y), fmaf(a, b.z, c.z), fmaf(a, b.w, c.w));
}
__device__ __forceinline__ float4 f4scale(float4 a, float s) {
    return make_float4(a.x * s, a.y * s, a.z * s, a.w * s);
}
__device__ __forceinline__ float4 f4add(float4 a, float4 b) {
    return make_float4(a.x + b.x, a.y + b.y, a.z + b.z, a.w + b.w);
}

// ---------------------------------------------------------------------------
// Pre-kernel: batch-invariant precomputation into d_ws
// ---------------------------------------------------------------------------
__global__ void hierec_pre(const float* __restrict__ subcat_embed,
                           const float* __restrict__ clicks_embed,
                           const float* __restrict__ w_subcat,
                           const float* __restrict__ w_cat,
                           float* __restrict__ ws)
{
    const int tid = threadIdx.x;
    const int lane = tid & 63;
    const int wave = tid >> 6;
    const int wpb = blockDim.x >> 6;
    const int gw = blockIdx.x * wpb + wave;
    const int nw = gridDim.x * wpb;

    // sce[s] = subcat_embed[s] . w_subcat[:D]
    for (int s = gw; s < SS; s += nw) {
        float p = 0.f;
        for (int d = lane; d < DD; d += 64) p += subcat_embed[s * DD + d] * w_subcat[d];
        for (int off = 32; off; off >>= 1) p += __shfl_down(p, off);
        if (lane == 0) ws[WS_SCE + s] = p;
    }
    if (blockIdx.x == 0) {
        // etot[d] = sum_s subcat_embed[s][d]
        for (int d = tid; d < DD; d += blockDim.x) {
            float a = 0.f;
            for (int s = 0; s < SS; ++s) a += subcat_embed[s * DD + d];
            ws[WS_ETOT + d] = a;
        }
    }
    if (blockIdx.x == 1) {
        // ced_sub[k] = clicks_embed[k] . w_subcat[D:], ced_cat[k] = . w_cat[D:]
        for (int k = wave; k < HH; k += wpb) {
            float p1 = 0.f, p2 = 0.f;
            if (lane < NCC) {
                float v = clicks_embed[k * NCC + lane];
                p1 = v * w_subcat[DD + lane];
                p2 = v * w_cat[DD + lane];
            }
            for (int off = 32; off; off >>= 1) {
                p1 += __shfl_down(p1, off);
                p2 += __shfl_down(p2, off);
            }
            if (lane == 0) { ws[WS_CEDS + k] = p1; ws[WS_CEDC + k] = p2; }
        }
    }
}

// ---------------------------------------------------------------------------
// Main fused kernel: one block per batch element
// ---------------------------------------------------------------------------
__global__ __launch_bounds__(BLOCK) void hierec_main(
    const float* __restrict__ vectors,      // [B,H,D]
    const int*   __restrict__ subcategory,  // [B,H]
    const int*   __restrict__ category,     // [B,H]
    const float* __restrict__ subcat_embed, // [S,D]
    const float* __restrict__ cat_embed,    // [C,D]
    const float* __restrict__ w_news,       // [D]
    const float* __restrict__ w_subcat,     // [D+NC]
    const float* __restrict__ w_cat,        // [D+NC]
    const float* __restrict__ pre,          // d_ws precomputed
    float* __restrict__ out)
{
    const int b    = blockIdx.x;
    const int tid  = threadIdx.x;
    const int lane = tid & 63;
    const int wave = tid >> 6;

    __shared__ float  catbuf[CC][DD];          // 28800 B
    __shared__ float4 vt4L[D4];                // vtot as float4
    __shared__ float4 et4L[D4];                // etot as float4
    __shared__ float  coefS[SS];               // per-s base coefficient (u/Z or 1/50)
    __shared__ unsigned long long maskS[SS];   // per-s member mask (0 if unclicked)
    __shared__ int    cntS[SS];                // per-s click count
    __shared__ float  ns1L[HH], ns2L[HH], uL[HH], ZL[HH], scL[HH], wNL[HH];
    __shared__ unsigned long long maskL[HH];
    __shared__ int    hsL[HH], hcL[HH], repL[HH], prepL[HH];
    __shared__ float  GmL[CC][HH];             // B_{c,h} coefficients
    __shared__ float  mcL[CC], ucL[CC], rZcL[CC], AL[CC], csL[CC], catwL[CC];
    __shared__ int    cntcL[CC];
    __shared__ int    prepCL[HH], prepSL[HH], prepJL[HH];
    __shared__ float  prepGL[HH];
    __shared__ int    npL;
    __shared__ float  PvL;

    const float*  vb  = vectors + (size_t)b * HH * DD;
    const float4* vb4 = (const float4*)vb;
    const float4* se4 = (const float4*)subcat_embed;

    // ---------------- P0/P1: ids, inits, per-row dots, vtot, etot copy ----------------
    if (tid < HH) {
        hsL[tid] = subcategory[b * HH + tid];
        hcL[tid] = category[b * HH + tid];
    }
    for (int s = tid; s < SS; s += BLOCK) {
        coefS[s] = 1.f / (float)HH;
        maskS[s] = 0ull;
        cntS[s]  = 0;
    }
    for (int h = wave; h < HH; h += 8) {
        float p1 = 0.f, p2 = 0.f;
        for (int d = lane; d < DD; d += 64) {
            float v = vb[h * DD + d];
            p1 += v * w_news[d];
            p2 += v * w_subcat[d];
        }
        for (int off = 32; off; off >>= 1) {
            p1 += __shfl_down(p1, off);
            p2 += __shfl_down(p2, off);
        }
        if (lane == 0) { ns1L[h] = p1; ns2L[h] = p2; }
    }
    if (tid < DD) {
        float a = 0.f;
        for (int h = 0; h < HH; ++h) a += vb[h * DD + tid];
        ((float*)vt4L)[tid] = a;
        ((float*)et4L)[tid] = pre[WS_ETOT + tid];
    }
    __syncthreads();

    // ---------------- P2: per-click softmax stats ----------------
    if (tid < HH) {
        const int h = tid;
        const int s = hsL[h], c = hcL[h];
        unsigned long long mask = 0ull, pmask = 0ull;
        for (int j = 0; j < HH; ++j) {
            bool ms = (hsL[j] == s);
            mask  |= (unsigned long long)(ms ? 1 : 0) << j;
            pmask |= (unsigned long long)((ms && hcL[j] == c) ? 1 : 0) << j;
        }
        int cnt = __popcll(mask);
        bool rep = ((__ffsll((long long)mask) - 1) == h);

        float m = FILLV;
        unsigned long long t = mask;
        while (t) { int j = __ffsll((long long)t) - 1; t &= t - 1; m = fmaxf(m, ns1L[j]); }
        float u = expf(FILLV - m);
        float sumE = 0.f, sum2 = 0.f;
        t = mask;
        while (t) {
            int j = __ffsll((long long)t) - 1; t &= t - 1;
            float e = expf(ns1L[j] - m);
            sumE += e;
            sum2 += (e - u) * ns2L[j];
        }
        float Z = sumE + (float)(HH - cnt) * u;
        float vt2 = 0.f;
        for (int j = 0; j < HH; ++j) vt2 += ns2L[j];
        int ci = cnt < (NCC - 1) ? cnt : (NCC - 1);
        float sc = (sum2 + u * vt2) / Z + pre[WS_SCE + s] + pre[WS_CEDS + ci];

        float e_h = expf(ns1L[h] - m);
        wNL[h] = (e_h - u) / Z;
        uL[h] = u; ZL[h] = Z; maskL[h] = mask; scL[h] = sc;
        repL[h]  = rep ? 1 : 0;
        prepL[h] = ((__ffsll((long long)pmask) - 1) == h) ? 1 : 0;
        if (rep) { coefS[s] = u / Z; maskS[s] = mask; cntS[s] = cnt; }
    }
    __syncthreads();

    // ---------------- P3a: per-category stats, Pv, prep list, small outputs ----------------
    if (tid < CC) {
        const int c = tid;
        float mc = FILLV; int n = 0, cc2 = 0;
        for (int j = 0; j < HH; ++j) {
            if (hcL[j] == c) ++cc2;
            if (prepL[j] && hcL[j] == c) { ++n; mc = fmaxf(mc, scL[j]); }
        }
        float u = expf(FILLV - mc);
        float sumE = 0.f;
        for (int j = 0; j < HH; ++j)
            if (prepL[j] && hcL[j] == c) sumE += expf(scL[j] - mc);
        float Zc = sumE + (float)(SS - n) * u;
        mcL[c] = mc; ucL[c] = u; rZcL[c] = 1.f / Zc; cntcL[c] = cc2;
        out[OFF3 + (size_t)b * CC + c] = (float)cc2 / (float)HH;
    }
    if (tid == 64) {
        int nd = 0, np = 0;
        float sumUb = 0.f;
        for (int j = 0; j < HH; ++j) {
            if (repL[j]) { ++nd; sumUb += uL[j] / ZL[j]; }
            if (prepL[j]) { prepCL[np] = hcL[j]; prepSL[np] = hsL[j]; prepJL[np] = j; ++np; }
        }
        npL = np;
        PvL = (float)(SS - nd) / (float)HH + sumUb;
    }
    for (int s = tid; s < SS; s += BLOCK)
        out[OFF1 + (size_t)b * SS + s] = (float)cntS[s] / (float)HH;
    __syncthreads();

    // ---------------- P3b: Gm (B coefficients), A_c, prep g values ----------------
    for (int idx = tid; idx < CC * HH; idx += BLOCK) {
        int c = idx / HH, h = idx - c * HH;
        bool exists = false;
        unsigned long long t = maskL[h];
        while (t) {
            int k = __ffsll((long long)t) - 1; t &= t - 1;
            if (hcL[k] == c) { exists = true; break; }
        }
        float g = exists ? (expf(scL[h] - mcL[c]) - ucL[c]) : 0.f;
        GmL[c][h] = wNL[h] * (ucL[c] + g);
    }
    if (tid < CC) {
        const int c = tid;
        float A = ucL[c] * PvL;
        for (int j = 0; j < HH; ++j)
            if (prepL[j] && hcL[j] == c)
                A += (expf(scL[j] - mcL[c]) - ucL[c]) * (uL[j] / ZL[j]);
        AL[c] = A;
    }
    for (int jj = tid; jj < npL; jj += BLOCK) {
        int j = prepJL[jj], c = prepCL[jj];
        prepGL[jj] = expf(scL[j] - mcL[c]) - ucL[c];
    }
    __syncthreads();

    // ---------------- P4: sub_repr — flat float4 streaming write ----------------
    {
        float4* o4 = (float4*)(out + (size_t)b * SS * DD);
        for (int i = tid; i < TOT4; i += BLOCK) {
            int s = i / D4;
            int q = i - s * D4;
            float4 e4  = se4[(size_t)s * D4 + q];
            float4 acc = f4scale(vt4L[q], coefS[s]);
            unsigned long long t = maskS[s];
            while (t) {
                int j = __ffsll((long long)t) - 1; t &= t - 1;
                acc = f4fma(wNL[j], vb4[j * D4 + q], acc);
            }
            o4[i] = f4add(acc, e4);
        }
    }

    // ---------------- P5: cat_repr — linearized coefficients, 3 c-rows per wave ----------------
    {
        const int c0 = wave, c1 = wave + 8, c2 = wave + 16;
        const bool has2 = (c2 < CC);
        const int np = npL;
        for (int d4 = lane; d4 < D4; d4 += 64) {
            float4 vt = vt4L[d4], et = et4L[d4];
            float4 a0 = f4fma(ucL[c0], et, f4scale(vt, AL[c0]));
            float4 a1 = f4fma(ucL[c1], et, f4scale(vt, AL[c1]));
            float4 a2 = has2 ? f4fma(ucL[c2], et, f4scale(vt, AL[c2]))
                             : make_float4(0.f, 0.f, 0.f, 0.f);
            for (int h = 0; h < HH; ++h) {
                float4 v = vb4[h * D4 + d4];
                a0 = f4fma(GmL[c0][h], v, a0);
                a1 = f4fma(GmL[c1][h], v, a1);
                if (has2) a2 = f4fma(GmL[c2][h], v, a2);
            }
            for (int jj = 0; jj < np; ++jj) {
                int pc = prepCL[jj];
                if (pc == c0 || pc == c1 || (has2 && pc == c2)) {
                    float4 e = se4[(size_t)prepSL[jj] * D4 + d4];
                    float g = prepGL[jj];
                    if (pc == c0) a0 = f4fma(g, e, a0);
                    else if (pc == c1) a1 = f4fma(g, e, a1);
                    else a2 = f4fma(g, e, a2);
                }
            }
            const float4* ce4 = (const float4*)cat_embed;
            float4* ocat = (float4*)(out + OFF2 + (size_t)b * CC * DD);
            float4 v0 = f4add(f4scale(a0, rZcL[c0]), ce4[c0 * D4 + d4]);
            float4 v1 = f4add(f4scale(a1, rZcL[c1]), ce4[c1 * D4 + d4]);
            ((float4*)&catbuf[c0][0])[d4] = v0;
            ((float4*)&catbuf[c1][0])[d4] = v1;
            ocat[c0 * D4 + d4] = v0;
            ocat[c1 * D4 + d4] = v1;
            if (has2) {
                float4 v2 = f4add(f4scale(a2, rZcL[c2]), ce4[c2 * D4 + d4]);
                ((float4*)&catbuf[c2][0])[d4] = v2;
                ocat[c2 * D4 + d4] = v2;
            }
        }
    }
    __syncthreads();

    // ---------------- P6: c_scores ----------------
    for (int c = wave; c < CC; c += 8) {
        float p = 0.f;
        for (int d = lane; d < DD; d += 64) p += catbuf[c][d] * w_cat[d];
        for (int off = 32; off; off >>= 1) p += __shfl_down(p, off);
        if (lane == 0) {
            int ci = cntcL[c] < (NCC - 1) ? cntcL[c] : (NCC - 1);
            csL[c] = p + pre[WS_CEDC + ci];
        }
    }
    __syncthreads();

    // ---------------- P7: softmax over C + user_repr ----------------
    if (tid < CC) {
        float m = csL[0];
        for (int j = 1; j < CC; ++j) m = fmaxf(m, csL[j]);
        float Zc = 0.f;
        for (int j = 0; j < CC; ++j) Zc += expf(csL[j] - m);
        catwL[tid] = expf(csL[tid] - m) / Zc;
    }
    __syncthreads();
    if (tid < DD) {
        float a = 0.f;
        for (int c = 0; c < CC; ++c) a += catwL[c] * catbuf[c][tid];
        out[OFF4 + (size_t)b * DD + tid] = a;
    }
}

extern "C" void kernel_launch(void* const* d_in, const int* in_sizes, int n_in,
                              void* d_out, int out_size, void* d_ws, size_t ws_size,
                              hipStream_t stream) {
    const float* vectors      = (const float*)d_in[0];
    const int*   subcategory  = (const int*)d_in[1];
    const int*   category     = (const int*)d_in[2];
    const float* subcat_embed = (const float*)d_in[3];
    const float* cat_embed    = (const float*)d_in[4];
    const float* clicks_embed = (const float*)d_in[5];
    const float* w_news       = (const float*)d_in[6];
    const float* w_subcat     = (const float*)d_in[7];
    const float* w_cat        = (const float*)d_in[8];
    float* out = (float*)d_out;
    float* ws  = (float*)d_ws;

    hipLaunchKernelGGL(hierec_pre, dim3(32), dim3(256), 0, stream,
                       subcat_embed, clicks_embed, w_subcat, w_cat, ws);
    hipLaunchKernelGGL(hierec_main, dim3(BB), dim3(BLOCK), 0, stream,
                       vectors, subcategory, category, subcat_embed, cat_embed,
                       w_news, w_subcat, w_cat, ws, out);
}

// Round 3
// 585.292 us; speedup vs baseline: 1.7649x; 1.0129x over previous
//
#include <hip/hip_runtime.h>

// Problem constants (match reference)
#define BB 2048
#define HH 50
#define DD 400
#define D4 100            // DD/4 float4 per row
#define SS 285
#define CC 18
#define NCC 50
#define FILLV 1e-30f

static constexpr int BLOCK = 256;
static constexpr int TOT4 = SS * D4;   // 28500 float4 of sub_repr per batch

// Output offsets (elements)
static constexpr size_t OFF1 = (size_t)BB * SS * DD;            // sub_weights
static constexpr size_t OFF2 = OFF1 + (size_t)BB * SS;          // cat_repr
static constexpr size_t OFF3 = OFF2 + (size_t)BB * CC * DD;     // cat_weights
static constexpr size_t OFF4 = OFF3 + (size_t)BB * CC;          // user_repr

// d_ws layout (floats)
#define WS_ETOT 0      // 400
#define WS_SCE  400    // 285  subcat_embed[s] . w_subcat[:D]
#define WS_SEW  688    // 285  subcat_embed[s] . w_cat[:D]
#define WS_CEDS 976    // 50   clicks_embed[k] . w_subcat[D:]
#define WS_CEDC 1026   // 50   clicks_embed[k] . w_cat[D:]
#define WS_CEW  1076   // 18   cat_embed[c] . w_cat[:D]

typedef float f4 __attribute__((ext_vector_type(4)));

// ---------------------------------------------------------------------------
// Pre-kernel: batch-invariant precomputation into d_ws
// ---------------------------------------------------------------------------
__global__ void hierec_pre(const float* __restrict__ subcat_embed,
                           const float* __restrict__ cat_embed,
                           const float* __restrict__ clicks_embed,
                           const float* __restrict__ w_subcat,
                           const float* __restrict__ w_cat,
                           float* __restrict__ ws)
{
    const int tid  = threadIdx.x;
    const int lane = tid & 63;
    const int wave = tid >> 6;
    const int wpb  = blockDim.x >> 6;
    const int gw   = blockIdx.x * wpb + wave;
    const int nw   = gridDim.x * wpb;

    // sce[s], sew[s]
    for (int s = gw; s < SS; s += nw) {
        float p1 = 0.f, p2 = 0.f;
        for (int d = lane; d < DD; d += 64) {
            float v = subcat_embed[s * DD + d];
            p1 += v * w_subcat[d];
            p2 += v * w_cat[d];
        }
        for (int off = 32; off; off >>= 1) {
            p1 += __shfl_down(p1, off);
            p2 += __shfl_down(p2, off);
        }
        if (lane == 0) { ws[WS_SCE + s] = p1; ws[WS_SEW + s] = p2; }
    }
    if (blockIdx.x == 0) {
        // etot[d] = sum_s subcat_embed[s][d]
        for (int d = tid; d < DD; d += blockDim.x) {
            float a = 0.f;
            for (int s = 0; s < SS; ++s) a += subcat_embed[s * DD + d];
            ws[WS_ETOT + d] = a;
        }
    }
    if (blockIdx.x == 1) {
        for (int k = wave; k < HH; k += wpb) {
            float p1 = 0.f, p2 = 0.f;
            if (lane < NCC) {
                float v = clicks_embed[k * NCC + lane];
                p1 = v * w_subcat[DD + lane];
                p2 = v * w_cat[DD + lane];
            }
            for (int off = 32; off; off >>= 1) {
                p1 += __shfl_down(p1, off);
                p2 += __shfl_down(p2, off);
            }
            if (lane == 0) { ws[WS_CEDS + k] = p1; ws[WS_CEDC + k] = p2; }
        }
    }
    if (blockIdx.x == 2) {
        // cew[c] = cat_embed[c] . w_cat[:D]
        for (int c = wave; c < CC; c += wpb) {
            float p = 0.f;
            for (int d = lane; d < DD; d += 64) p += cat_embed[c * DD + d] * w_cat[d];
            for (int off = 32; off; off >>= 1) p += __shfl_down(p, off);
            if (lane == 0) ws[WS_CEW + c] = p;
        }
    }
}

// ---------------------------------------------------------------------------
// Main fused kernel: one block (256 thr) per batch element, ~15 KB LDS
// ---------------------------------------------------------------------------
__global__ __launch_bounds__(BLOCK, 8) void hierec_main(
    const float* __restrict__ vectors,      // [B,H,D]
    const int*   __restrict__ subcategory,  // [B,H]
    const int*   __restrict__ category,     // [B,H]
    const float* __restrict__ subcat_embed, // [S,D]
    const float* __restrict__ cat_embed,    // [C,D]
    const float* __restrict__ w_news,       // [D]
    const float* __restrict__ w_subcat,     // [D+NC]
    const float* __restrict__ w_cat,        // [D+NC]
    const float* __restrict__ pre,          // d_ws precomputed
    float* __restrict__ out)
{
    const int b    = blockIdx.x;
    const int tid  = threadIdx.x;
    const int lane = tid & 63;
    const int wave = tid >> 6;

    __shared__ f4     vt4L[D4];                // vtot
    __shared__ f4     et4L[D4];                // etot
    __shared__ float  coefS[SS];
    __shared__ unsigned long long maskS[SS];
    __shared__ int    cntS[SS];
    __shared__ float  ns1L[HH], ns2L[HH], ns3L[HH];
    __shared__ float  uzL[HH], wNL[HH], scL[HH];
    __shared__ unsigned long long maskL[HH];
    __shared__ int    hsL[HH], hcL[HH], repL[HH], prepL[HH];
    __shared__ float  GmL[CC][HH];
    __shared__ float  mcL[CC], ucL[CC], rZcL[CC], AL[CC], csL[CC], catwL[CC];
    __shared__ int    cntcL[CC];
    __shared__ int    prepCL[HH], prepSL[HH], prepJL[HH];
    __shared__ float  prepGL[HH], uPL[HH], uGL[HH];
    __shared__ int    npL;
    __shared__ float  PvL, vtwL, etwL, uAL, uEL;

    const float* vb  = vectors + (size_t)b * HH * DD;
    const f4*    vb4 = (const f4*)vb;
    const f4*    se4 = (const f4*)subcat_embed;
    const f4*    ce4 = (const f4*)cat_embed;

    // ---------------- P0: ids + inits ----------------
    if (tid < HH) {
        hsL[tid] = subcategory[b * HH + tid];
        hcL[tid] = category[b * HH + tid];
    }
    for (int s = tid; s < SS; s += BLOCK) {
        coefS[s] = 1.f / (float)HH;
        maskS[s] = 0ull;
        cntS[s]  = 0;
    }
    __syncthreads();

    // ---------------- P1: row dots (ns1,ns2,ns3), vtot, etot copy ----------------
    for (int h = wave; h < HH; h += 4) {
        float p1 = 0.f, p2 = 0.f, p3 = 0.f;
        for (int d = lane; d < DD; d += 64) {
            float v = vb[h * DD + d];
            p1 += v * w_news[d];
            p2 += v * w_subcat[d];
            p3 += v * w_cat[d];
        }
        for (int off = 32; off; off >>= 1) {
            p1 += __shfl_down(p1, off);
            p2 += __shfl_down(p2, off);
            p3 += __shfl_down(p3, off);
        }
        if (lane == 0) { ns1L[h] = p1; ns2L[h] = p2; ns3L[h] = p3; }
    }
    if (tid < D4) {
        f4 a = {0.f, 0.f, 0.f, 0.f};
        #pragma unroll 5
        for (int h = 0; h < HH; ++h) a += vb4[h * D4 + tid];
        vt4L[tid] = a;
        et4L[tid] = ((const f4*)pre)[tid];   // WS_ETOT == 0
    }
    __syncthreads();

    // ---------------- P2: per-click stats (wave 0) + etw (wave 1) + vtw (wave 2) --
    if (tid < HH) {
        const int h = tid;
        const int s = hsL[h], c = hcL[h];
        unsigned long long mask = 0ull, pmask = 0ull;
        for (int j = 0; j < HH; ++j) {
            bool ms = (hsL[j] == s);
            mask  |= (unsigned long long)(ms ? 1 : 0) << j;
            pmask |= (unsigned long long)((ms && hcL[j] == c) ? 1 : 0) << j;
        }
        int cnt = __popcll(mask);
        bool rep = ((__ffsll((long long)mask) - 1) == h);

        float m = FILLV;
        unsigned long long t = mask;
        while (t) { int j = __ffsll((long long)t) - 1; t &= t - 1; m = fmaxf(m, ns1L[j]); }
        float u = expf(FILLV - m);
        float sumE = 0.f, sum2 = 0.f;
        t = mask;
        while (t) {
            int j = __ffsll((long long)t) - 1; t &= t - 1;
            float e = expf(ns1L[j] - m);
            sumE += e;
            sum2 += (e - u) * ns2L[j];
        }
        float Z = sumE + (float)(HH - cnt) * u;
        float vt2 = 0.f;
        for (int j = 0; j < HH; ++j) vt2 += ns2L[j];
        int ci = cnt < (NCC - 1) ? cnt : (NCC - 1);
        float sc = (sum2 + u * vt2) / Z + pre[WS_SCE + s] + pre[WS_CEDS + ci];

        float e_h = expf(ns1L[h] - m);
        float uz = u / Z;
        wNL[h] = (e_h - u) / Z;
        uzL[h] = uz; maskL[h] = mask; scL[h] = sc;
        repL[h]  = rep ? 1 : 0;
        prepL[h] = ((__ffsll((long long)pmask) - 1) == h) ? 1 : 0;
        if (rep) { coefS[s] = uz; maskS[s] = mask; cntS[s] = cnt; }
    } else if (wave == 1) {
        // etw = etot . w_cat
        float p = 0.f;
        const float* et = (const float*)et4L;
        for (int d = lane; d < DD; d += 64) p += et[d] * w_cat[d];
        for (int off = 32; off; off >>= 1) p += __shfl_down(p, off);
        if (lane == 0) etwL = p;
    } else if (wave == 2) {
        // vtw = sum_h ns3[h]
        float p = (lane < HH) ? ns3L[lane] : 0.f;
        for (int off = 32; off; off >>= 1) p += __shfl_down(p, off);
        if (lane == 0) vtwL = p;
    }
    __syncthreads();

    // ---------------- P3a: per-category stats, prep list, small outputs --------
    if (tid < CC) {
        const int c = tid;
        float mc = FILLV; int n = 0, cc2 = 0;
        for (int j = 0; j < HH; ++j) {
            if (hcL[j] == c) ++cc2;
            if (prepL[j] && hcL[j] == c) { ++n; mc = fmaxf(mc, scL[j]); }
        }
        float u = expf(FILLV - mc);
        float sumE = 0.f;
        for (int j = 0; j < HH; ++j)
            if (prepL[j] && hcL[j] == c) sumE += expf(scL[j] - mc);
        float Zc = sumE + (float)(SS - n) * u;
        mcL[c] = mc; ucL[c] = u; rZcL[c] = 1.f / Zc; cntcL[c] = cc2;
        __builtin_nontemporal_store((float)cc2 * (1.f / (float)HH),
                                    &out[OFF3 + (size_t)b * CC + c]);
    }
    if (tid == 64) {
        int nd = 0, np = 0;
        float sumUb = 0.f;
        for (int j = 0; j < HH; ++j) {
            if (repL[j]) { ++nd; sumUb += uzL[j]; }
            if (prepL[j]) { prepCL[np] = hcL[j]; prepSL[np] = hsL[j]; prepJL[np] = j; ++np; }
        }
        npL = np;
        PvL = (float)(SS - nd) * (1.f / (float)HH) + sumUb;
    }
    for (int s = tid; s < SS; s += BLOCK)
        __builtin_nontemporal_store((float)cntS[s] * (1.f / (float)HH),
                                    &out[OFF1 + (size_t)b * SS + s]);
    __syncthreads();

    // ---------------- P3b: Gm coefficients, A_c, prep g ----------------
    for (int idx = tid; idx < CC * HH; idx += BLOCK) {
        int c = idx / HH, h = idx - c * HH;
        bool exists = false;
        unsigned long long t = maskL[h];
        while (t) {
            int k = __ffsll((long long)t) - 1; t &= t - 1;
            if (hcL[k] == c) { exists = true; break; }
        }
        float g = exists ? (expf(scL[h] - mcL[c]) - ucL[c]) : 0.f;
        GmL[c][h] = wNL[h] * (ucL[c] + g);
    }
    if (tid < CC) {
        const int c = tid;
        float A = ucL[c] * PvL;
        for (int j = 0; j < HH; ++j)
            if (prepL[j] && hcL[j] == c)
                A += (expf(scL[j] - mcL[c]) - ucL[c]) * uzL[j];
        AL[c] = A;
    }
    __syncthreads();
    if (tid >= 64 && tid < 64 + HH) {
        int jj = tid - 64;
        if (jj < npL) {
            int j = prepJL[jj], c = prepCL[jj];
            prepGL[jj] = expf(scL[j] - mcL[c]) - ucL[c];
        }
    }
    __syncthreads();

    // ---------------- P6a: c_scores, pure scalar ----------------
    if (tid < CC) {
        const int c = tid;
        float sG = 0.f;
        for (int h = 0; h < HH; ++h) sG += GmL[c][h] * ns3L[h];
        float sP = 0.f;
        const int np = npL;
        for (int jj = 0; jj < np; ++jj)
            if (prepCL[jj] == c) sP += prepGL[jj] * pre[WS_SEW + prepSL[jj]];
        int ci = cntcL[c] < (NCC - 1) ? cntcL[c] : (NCC - 1);
        csL[c] = rZcL[c] * (AL[c] * vtwL + ucL[c] * etwL + sG + sP)
                 + pre[WS_CEW + c] + pre[WS_CEDC + ci];
    }
    __syncthreads();

    // ---------------- P6b: cat softmax + user-repr coefficient vector ----------
    if (tid < CC) {
        float m = csL[0];
        for (int j = 1; j < CC; ++j) m = fmaxf(m, csL[j]);
        float Zc = 0.f;
        for (int j = 0; j < CC; ++j) Zc += expf(csL[j] - m);
        catwL[tid] = expf(csL[tid] - m) / Zc;
    }
    __syncthreads();
    if (tid < HH) {
        float g = 0.f;
        for (int c = 0; c < CC; ++c) g += catwL[c] * rZcL[c] * GmL[c][tid];
        uGL[tid] = g;
    }
    if (tid == 64) {
        float uA = 0.f, uE = 0.f;
        for (int c = 0; c < CC; ++c) {
            uA += catwL[c] * rZcL[c] * AL[c];
            uE += catwL[c] * rZcL[c] * ucL[c];
        }
        uAL = uA; uEL = uE;
    }
    if (tid >= 128 && tid < 128 + HH) {
        int jj = tid - 128;
        if (jj < npL) {
            int c = prepCL[jj];
            uPL[jj] = catwL[c] * rZcL[c] * prepGL[jj];
        }
    }
    __syncthreads();

    // ======== Heavy streaming section — NO barriers from here on ========

    // ---------------- P5: cat_repr [C,D] ----------------
    {
        f4* oc = (f4*)(out + OFF2 + (size_t)b * CC * DD);
        const int np = npL;
        for (int i = tid; i < CC * D4; i += BLOCK) {
            int c = i / D4, q = i - c * D4;
            f4 acc = AL[c] * vt4L[q] + ucL[c] * et4L[q];
            #pragma unroll 5
            for (int h = 0; h < HH; ++h) acc += GmL[c][h] * vb4[h * D4 + q];
            for (int jj = 0; jj < np; ++jj)
                if (prepCL[jj] == c) acc += prepGL[jj] * se4[prepSL[jj] * D4 + q];
            acc = rZcL[c] * acc + ce4[i];
            __builtin_nontemporal_store(acc, &oc[i]);
        }
    }

    // ---------------- P7: user_repr [D] ----------------
    {
        f4* ou = (f4*)(out + OFF4 + (size_t)b * DD);
        const int np = npL;
        for (int q = tid; q < D4; q += BLOCK) {
            f4 acc = uAL * vt4L[q] + uEL * et4L[q];
            #pragma unroll 5
            for (int h = 0; h < HH; ++h) acc += uGL[h] * vb4[h * D4 + q];
            for (int jj = 0; jj < np; ++jj) acc += uPL[jj] * se4[prepSL[jj] * D4 + q];
            for (int c = 0; c < CC; ++c) acc += catwL[c] * ce4[c * D4 + q];
            __builtin_nontemporal_store(acc, &ou[q]);
        }
    }

    // ---------------- P4: sub_repr [S,D] — the big streaming write -----------
    {
        f4* o4 = (f4*)(out + (size_t)b * SS * DD);
        for (int i = tid; i < TOT4; i += BLOCK) {
            int s = i / D4;
            int q = i - s * D4;
            f4 acc = coefS[s] * vt4L[q] + se4[i];
            unsigned long long t = maskS[s];
            while (t) {
                int j = __ffsll((long long)t) - 1; t &= t - 1;
                acc += wNL[j] * vb4[j * D4 + q];
            }
            __builtin_nontemporal_store(acc, &o4[i]);
        }
    }
}

extern "C" void kernel_launch(void* const* d_in, const int* in_sizes, int n_in,
                              void* d_out, int out_size, void* d_ws, size_t ws_size,
                              hipStream_t stream) {
    const float* vectors      = (const float*)d_in[0];
    const int*   subcategory  = (const int*)d_in[1];
    const int*   category     = (const int*)d_in[2];
    const float* subcat_embed = (const float*)d_in[3];
    const float* cat_embed    = (const float*)d_in[4];
    const float* clicks_embed = (const float*)d_in[5];
    const float* w_news       = (const float*)d_in[6];
    const float* w_subcat     = (const float*)d_in[7];
    const float* w_cat        = (const float*)d_in[8];
    float* out = (float*)d_out;
    float* ws  = (float*)d_ws;

    hipLaunchKernelGGL(hierec_pre, dim3(32), dim3(256), 0, stream,
                       subcat_embed, cat_embed, clicks_embed, w_subcat, w_cat, ws);
    hipLaunchKernelGGL(hierec_main, dim3(BB), dim3(BLOCK), 0, stream,
                       vectors, subcategory, category, subcat_embed, cat_embed,
                       w_news, w_subcat, w_cat, ws, out);
}

// Round 4
// 512.184 us; speedup vs baseline: 2.0168x; 1.1427x over previous
//
#include <hip/hip_runtime.h>

// Problem constants (match reference)
#define BB 2048
#define HH 50
#define DD 400
#define D4 100            // DD/4 float4 per row
#define SS 285
#define CC 18
#define NCC 50
#define FILLV 1e-30f

static constexpr int BLOCK = 256;

// Output offsets (elements)
static constexpr size_t OFF1 = (size_t)BB * SS * DD;            // sub_weights
static constexpr size_t OFF2 = OFF1 + (size_t)BB * SS;          // cat_repr
static constexpr size_t OFF3 = OFF2 + (size_t)BB * CC * DD;     // cat_weights
static constexpr size_t OFF4 = OFF3 + (size_t)BB * CC;          // user_repr

// d_ws layout (floats)
#define WS_ETOT 0      // 400
#define WS_SCE  400    // 285  subcat_embed[s] . w_subcat[:D]
#define WS_SEW  688    // 285  subcat_embed[s] . w_cat[:D]
#define WS_CEDS 976    // 50   clicks_embed[k] . w_subcat[D:]
#define WS_CEDC 1026   // 50   clicks_embed[k] . w_cat[D:]
#define WS_CEW  1076   // 18   cat_embed[c] . w_cat[:D]

typedef float f4 __attribute__((ext_vector_type(4)));

__device__ __forceinline__ float dot4(f4 a, f4 b) {
    return a.x * b.x + a.y * b.y + a.z * b.z + a.w * b.w;
}

// ---------------------------------------------------------------------------
// Pre-kernel: batch-invariant precomputation into d_ws
// ---------------------------------------------------------------------------
__global__ void hierec_pre(const float* __restrict__ subcat_embed,
                           const float* __restrict__ cat_embed,
                           const float* __restrict__ clicks_embed,
                           const float* __restrict__ w_subcat,
                           const float* __restrict__ w_cat,
                           float* __restrict__ ws)
{
    const int tid  = threadIdx.x;
    const int lane = tid & 63;
    const int wave = tid >> 6;
    const int wpb  = blockDim.x >> 6;
    const int gw   = blockIdx.x * wpb + wave;
    const int nw   = gridDim.x * wpb;

    for (int s = gw; s < SS; s += nw) {
        float p1 = 0.f, p2 = 0.f;
        for (int d = lane; d < DD; d += 64) {
            float v = subcat_embed[s * DD + d];
            p1 += v * w_subcat[d];
            p2 += v * w_cat[d];
        }
        for (int off = 32; off; off >>= 1) {
            p1 += __shfl_down(p1, off);
            p2 += __shfl_down(p2, off);
        }
        if (lane == 0) { ws[WS_SCE + s] = p1; ws[WS_SEW + s] = p2; }
    }
    if (blockIdx.x == 0) {
        for (int d = tid; d < DD; d += blockDim.x) {
            float a = 0.f;
            for (int s = 0; s < SS; ++s) a += subcat_embed[s * DD + d];
            ws[WS_ETOT + d] = a;
        }
    }
    if (blockIdx.x == 1) {
        for (int k = wave; k < HH; k += wpb) {
            float p1 = 0.f, p2 = 0.f;
            if (lane < NCC) {
                float v = clicks_embed[k * NCC + lane];
                p1 = v * w_subcat[DD + lane];
                p2 = v * w_cat[DD + lane];
            }
            for (int off = 32; off; off >>= 1) {
                p1 += __shfl_down(p1, off);
                p2 += __shfl_down(p2, off);
            }
            if (lane == 0) { ws[WS_CEDS + k] = p1; ws[WS_CEDC + k] = p2; }
        }
    }
    if (blockIdx.x == 2) {
        for (int c = wave; c < CC; c += wpb) {
            float p = 0.f;
            for (int d = lane; d < DD; d += 64) p += cat_embed[c * DD + d] * w_cat[d];
            for (int off = 32; off; off >>= 1) p += __shfl_down(p, off);
            if (lane == 0) ws[WS_CEW + c] = p;
        }
    }
}

// ---------------------------------------------------------------------------
// Main fused kernel: one block (256 thr) per batch element, ~17 KB LDS
// ---------------------------------------------------------------------------
__global__ __launch_bounds__(BLOCK, 8) void hierec_main(
    const float* __restrict__ vectors,      // [B,H,D]
    const int*   __restrict__ subcategory,  // [B,H]
    const int*   __restrict__ category,     // [B,H]
    const float* __restrict__ subcat_embed, // [S,D]
    const float* __restrict__ cat_embed,    // [C,D]
    const float* __restrict__ w_news,       // [D]
    const float* __restrict__ w_subcat,     // [D+NC]
    const float* __restrict__ w_cat,        // [D+NC]
    const float* __restrict__ pre,          // d_ws precomputed
    float* __restrict__ out)
{
    const int b    = blockIdx.x;
    const int tid  = threadIdx.x;
    const int lane = tid & 63;
    const int wave = tid >> 6;

    __shared__ f4     vt4L[D4];
    __shared__ f4     et4L[D4];
    __shared__ float  coefS[SS];
    __shared__ unsigned long long maskS[SS];
    __shared__ int    cntS[SS];
    __shared__ float  ns1L[HH], ns2L[HH], ns3L[HH];
    __shared__ float  uzL[HH], wNL[HH], scL[HH];
    __shared__ unsigned long long maskL[HH];
    __shared__ int    hsL[HH], hcL[HH], repL[HH], prepL[HH];
    __shared__ float  GmL[CC][HH];
    __shared__ float  mcL[CC], ucL[CC], rZcL[CC], AL[CC], csL[CC], catwL[CC];
    __shared__ int    cntcL[CC];
    __shared__ int    prepCL[HH], prepSL[HH];
    __shared__ float  prepGL[HH];
    __shared__ int    clickedL[HH];
    __shared__ int    unclkL[SS];
    __shared__ int    npL, ndL, nUcnt;
    __shared__ float  PvL, vtwL, etwL;

    const float* vb  = vectors + (size_t)b * HH * DD;
    const f4*    vb4 = (const f4*)vb;
    const f4*    se4 = (const f4*)subcat_embed;
    const f4*    ce4 = (const f4*)cat_embed;

    // ---------------- P0: ids + inits ----------------
    if (tid < HH) {
        hsL[tid] = subcategory[b * HH + tid];
        hcL[tid] = category[b * HH + tid];
    }
    for (int s = tid; s < SS; s += BLOCK) {
        coefS[s] = 1.f / (float)HH;
        maskS[s] = 0ull;
        cntS[s]  = 0;
    }
    if (tid < D4) {
        et4L[tid] = ((const f4*)pre)[tid];   // WS_ETOT == 0
        f4 z = {0.f, 0.f, 0.f, 0.f};
        vt4L[tid] = z;
    }
    if (tid == 0) nUcnt = 0;
    __syncthreads();

    // ---------------- A: single vb pass — 3 dots + vtot partials ----------------
    {
        const f4* wn4 = (const f4*)w_news;
        const f4* ws4 = (const f4*)w_subcat;
        const f4* wc4 = (const f4*)w_cat;
        const bool hi = lane < (D4 - 64);   // lanes 0..35 also cover d4 = 64+lane
        f4 vtp0 = {0.f, 0.f, 0.f, 0.f};
        f4 vtp1 = {0.f, 0.f, 0.f, 0.f};
        for (int h = wave; h < HH; h += 4) {
            f4 v0 = __builtin_nontemporal_load(&vb4[h * D4 + lane]);
            float p1 = dot4(v0, wn4[lane]);
            float p2 = dot4(v0, ws4[lane]);
            float p3 = dot4(v0, wc4[lane]);
            vtp0 += v0;
            if (hi) {
                f4 v1 = __builtin_nontemporal_load(&vb4[h * D4 + 64 + lane]);
                p1 += dot4(v1, wn4[64 + lane]);
                p2 += dot4(v1, ws4[64 + lane]);
                p3 += dot4(v1, wc4[64 + lane]);
                vtp1 += v1;
            }
            for (int off = 32; off; off >>= 1) {
                p1 += __shfl_down(p1, off);
                p2 += __shfl_down(p2, off);
                p3 += __shfl_down(p3, off);
            }
            if (lane == 0) { ns1L[h] = p1; ns2L[h] = p2; ns3L[h] = p3; }
        }
        float* vtf = (float*)vt4L;
        atomicAdd(&vtf[4 * lane + 0], vtp0.x);
        atomicAdd(&vtf[4 * lane + 1], vtp0.y);
        atomicAdd(&vtf[4 * lane + 2], vtp0.z);
        atomicAdd(&vtf[4 * lane + 3], vtp0.w);
        if (hi) {
            atomicAdd(&vtf[4 * (64 + lane) + 0], vtp1.x);
            atomicAdd(&vtf[4 * (64 + lane) + 1], vtp1.y);
            atomicAdd(&vtf[4 * (64 + lane) + 2], vtp1.z);
            atomicAdd(&vtf[4 * (64 + lane) + 3], vtp1.w);
        }
    }
    __syncthreads();

    // ---------------- P2: per-click stats (w0) + etw (w1) + vtw (w2) ----------
    if (tid < HH) {
        const int h = tid;
        const int s = hsL[h], c = hcL[h];
        unsigned long long mask = 0ull, pmask = 0ull;
        for (int j = 0; j < HH; ++j) {
            bool ms = (hsL[j] == s);
            mask  |= (unsigned long long)(ms ? 1 : 0) << j;
            pmask |= (unsigned long long)((ms && hcL[j] == c) ? 1 : 0) << j;
        }
        int cnt = __popcll(mask);
        bool rep = ((__ffsll((long long)mask) - 1) == h);

        float m = FILLV;
        unsigned long long t = mask;
        while (t) { int j = __ffsll((long long)t) - 1; t &= t - 1; m = fmaxf(m, ns1L[j]); }
        float u = expf(FILLV - m);
        float sumE = 0.f, sum2 = 0.f;
        t = mask;
        while (t) {
            int j = __ffsll((long long)t) - 1; t &= t - 1;
            float e = expf(ns1L[j] - m);
            sumE += e;
            sum2 += (e - u) * ns2L[j];
        }
        float Z = sumE + (float)(HH - cnt) * u;
        float vt2 = 0.f;
        for (int j = 0; j < HH; ++j) vt2 += ns2L[j];
        int ci = cnt < (NCC - 1) ? cnt : (NCC - 1);
        float sc = (sum2 + u * vt2) / Z + pre[WS_SCE + s] + pre[WS_CEDS + ci];

        float e_h = expf(ns1L[h] - m);
        float uz = u / Z;
        wNL[h] = (e_h - u) / Z;
        uzL[h] = uz; maskL[h] = mask; scL[h] = sc;
        repL[h]  = rep ? 1 : 0;
        prepL[h] = ((__ffsll((long long)pmask) - 1) == h) ? 1 : 0;
        if (rep) { coefS[s] = uz; maskS[s] = mask; cntS[s] = cnt; }
    } else if (wave == 1) {
        float p = 0.f;
        const float* et = (const float*)et4L;
        for (int d = lane; d < DD; d += 64) p += et[d] * w_cat[d];
        for (int off = 32; off; off >>= 1) p += __shfl_down(p, off);
        if (lane == 0) etwL = p;
    } else if (wave == 2) {
        float p = (lane < HH) ? ns3L[lane] : 0.f;
        for (int off = 32; off; off >>= 1) p += __shfl_down(p, off);
        if (lane == 0) vtwL = p;
    }
    __syncthreads();

    // ---------------- P3a: per-c stats, lists, small outputs ----------------
    if (tid < CC) {
        const int c = tid;
        float mc = FILLV; int n = 0, cc2 = 0;
        for (int j = 0; j < HH; ++j) {
            if (hcL[j] == c) ++cc2;
            if (prepL[j] && hcL[j] == c) { ++n; mc = fmaxf(mc, scL[j]); }
        }
        float u = expf(FILLV - mc);
        float sumE = 0.f;
        for (int j = 0; j < HH; ++j)
            if (prepL[j] && hcL[j] == c) sumE += expf(scL[j] - mc);
        float Zc = sumE + (float)(SS - n) * u;
        mcL[c] = mc; ucL[c] = u; rZcL[c] = 1.f / Zc; cntcL[c] = cc2;
        __builtin_nontemporal_store((float)cc2 * (1.f / (float)HH),
                                    &out[OFF3 + (size_t)b * CC + c]);
    }
    if (tid == 64) {
        int nd = 0, np = 0;
        float sumUb = 0.f;
        for (int j = 0; j < HH; ++j) {
            if (repL[j]) { clickedL[nd] = hsL[j]; ++nd; sumUb += uzL[j]; }
            if (prepL[j]) { prepCL[np] = hcL[j]; prepSL[np] = hsL[j]; ++np; }
        }
        npL = np; ndL = nd;
        PvL = (float)(SS - nd) * (1.f / (float)HH) + sumUb;
    }
    for (int s = tid; s < SS; s += BLOCK) {
        __builtin_nontemporal_store((float)cntS[s] * (1.f / (float)HH),
                                    &out[OFF1 + (size_t)b * SS + s]);
        if (maskS[s] == 0ull) {
            int p = atomicAdd(&nUcnt, 1);
            unclkL[p] = s;
        }
    }
    __syncthreads();

    // ---------------- P3b: Gm coefficients, A_c, prep g ----------------
    for (int idx = tid; idx < CC * HH; idx += BLOCK) {
        int c = idx / HH, h = idx - c * HH;
        bool exists = false;
        unsigned long long t = maskL[h];
        while (t) {
            int k = __ffsll((long long)t) - 1; t &= t - 1;
            if (hcL[k] == c) { exists = true; break; }
        }
        float g = exists ? (expf(scL[h] - mcL[c]) - ucL[c]) : 0.f;
        GmL[c][h] = wNL[h] * (ucL[c] + g);
    }
    if (tid < CC) {
        const int c = tid;
        float A = ucL[c] * PvL;
        for (int j = 0; j < HH; ++j)
            if (prepL[j] && hcL[j] == c)
                A += (expf(scL[j] - mcL[c]) - ucL[c]) * uzL[j];
        AL[c] = A;
    }
    if (tid >= 64 && tid < 64 + HH) {
        int jj = tid - 64;
        if (jj < HH) {
            // prepGL valid only for jj < npL; compute guarded via prep arrays
            // (prepCL/SL written by thread 64 last barrier)
        }
    }
    __syncthreads();
    if (tid < HH && tid < npL) {
        int c = prepCL[tid];
        // find the h for this prep entry: it is the prep representative with this (c,s);
        // we stored only c,s — recompute g from the first prep h matching:
        // simpler: iterate h to find prep h with hc==c && hs==prepSL
        int s = prepSL[tid];
        float g = 0.f;
        for (int j = 0; j < HH; ++j)
            if (prepL[j] && hcL[j] == c && hsL[j] == s) { g = expf(scL[j] - mcL[c]) - ucL[c]; break; }
        prepGL[tid] = g;
    }
    __syncthreads();

    // ---------------- P6a: c_scores (scalar) ----------------
    if (tid < CC) {
        const int c = tid;
        float sG = 0.f;
        for (int h = 0; h < HH; ++h) sG += GmL[c][h] * ns3L[h];
        float sP = 0.f;
        const int np = npL;
        for (int jj = 0; jj < np; ++jj)
            if (prepCL[jj] == c) sP += prepGL[jj] * pre[WS_SEW + prepSL[jj]];
        int ci = cntcL[c] < (NCC - 1) ? cntcL[c] : (NCC - 1);
        csL[c] = rZcL[c] * (AL[c] * vtwL + ucL[c] * etwL + sG + sP)
                 + pre[WS_CEW + c] + pre[WS_CEDC + ci];
    }
    __syncthreads();

    // ---------------- P6b: cat softmax ----------------
    if (tid < CC) {
        float m = csL[0];
        for (int j = 1; j < CC; ++j) m = fmaxf(m, csL[j]);
        float Zc = 0.f;
        for (int j = 0; j < CC; ++j) Zc += expf(csL[j] - m);
        catwL[tid] = expf(csL[tid] - m) / Zc;
    }
    __syncthreads();

    // ======== Heavy streaming section — no more barriers ========

    // ---------------- C: cat_repr + user_repr, thread-per-q ----------------
    if (tid < D4) {
        const int q = tid;
        const int np = npL;
        f4 uacc = {0.f, 0.f, 0.f, 0.f};
        f4* oc = (f4*)(out + OFF2 + (size_t)b * CC * DD);
        #pragma unroll 1
        for (int c0 = 0; c0 < CC; c0 += 6) {
            f4 vt = vt4L[q], et = et4L[q];
            f4 a[6];
            #pragma unroll
            for (int cc = 0; cc < 6; ++cc) {
                int c = c0 + cc;
                a[cc] = AL[c] * vt + ucL[c] * et;
            }
            for (int h = 0; h < HH; ++h) {
                f4 v = __builtin_nontemporal_load(&vb4[h * D4 + q]);
                #pragma unroll
                for (int cc = 0; cc < 6; ++cc) a[cc] += GmL[c0 + cc][h] * v;
            }
            #pragma unroll
            for (int cc = 0; cc < 6; ++cc) {
                int c = c0 + cc;
                f4 acc = a[cc];
                for (int jj = 0; jj < np; ++jj)
                    if (prepCL[jj] == c) acc += prepGL[jj] * se4[prepSL[jj] * D4 + q];
                acc = rZcL[c] * acc + ce4[c * D4 + q];
                uacc += catwL[c] * acc;
                __builtin_nontemporal_store(acc, &oc[c * D4 + q]);
            }
        }
        f4* ou = (f4*)(out + OFF4 + (size_t)b * DD);
        __builtin_nontemporal_store(uacc, &ou[q]);
    }

    // ---------------- D-clicked: sub_repr rows needing corrections ----------
    f4* o4 = (f4*)(out + (size_t)b * SS * DD);
    {
        const int tot = ndL * D4;
        for (int i = tid; i < tot; i += BLOCK) {
            int ii = i / D4;
            int q  = i - ii * D4;
            int s  = clickedL[ii];
            f4 acc = coefS[s] * vt4L[q] + se4[s * D4 + q];
            unsigned long long t = maskS[s];
            while (t) {
                int j = __ffsll((long long)t) - 1; t &= t - 1;
                acc += wNL[j] * __builtin_nontemporal_load(&vb4[j * D4 + q]);
            }
            __builtin_nontemporal_store(acc, &o4[s * D4 + q]);
        }
    }

    // ---------------- D-fast: unclicked rows — pure stream ----------------
    {
        const int tot = (SS - ndL) * D4;
        const float cst = 1.f / (float)HH;
        for (int i = tid; i < tot; i += BLOCK) {
            int u = i / D4;
            int q = i - u * D4;
            int s = unclkL[u];
            f4 acc = cst * vt4L[q] + se4[s * D4 + q];
            __builtin_nontemporal_store(acc, &o4[s * D4 + q]);
        }
    }
}

extern "C" void kernel_launch(void* const* d_in, const int* in_sizes, int n_in,
                              void* d_out, int out_size, void* d_ws, size_t ws_size,
                              hipStream_t stream) {
    const float* vectors      = (const float*)d_in[0];
    const int*   subcategory  = (const int*)d_in[1];
    const int*   category     = (const int*)d_in[2];
    const float* subcat_embed = (const float*)d_in[3];
    const float* cat_embed    = (const float*)d_in[4];
    const float* clicks_embed = (const float*)d_in[5];
    const float* w_news       = (const float*)d_in[6];
    const float* w_subcat     = (const float*)d_in[7];
    const float* w_cat        = (const float*)d_in[8];
    float* out = (float*)d_out;
    float* ws  = (float*)d_ws;

    hipLaunchKernelGGL(hierec_pre, dim3(32), dim3(256), 0, stream,
                       subcat_embed, cat_embed, clicks_embed, w_subcat, w_cat, ws);
    hipLaunchKernelGGL(hierec_main, dim3(BB), dim3(BLOCK), 0, stream,
                       vectors, subcategory, category, subcat_embed, cat_embed,
                       w_news, w_subcat, w_cat, ws, out);
}

// Round 5
// 511.945 us; speedup vs baseline: 2.0177x; 1.0005x over previous
//
#include <hip/hip_runtime.h>

// Problem constants (match reference)
#define BB 2048
#define HH 50
#define DD 400
#define D4 100            // DD/4 float4 per row
#define SS 285
#define CC 18
#define NCC 50
#define FILLV 1e-30f

static constexpr int BLOCK = 256;

// Output offsets (elements)
static constexpr size_t OFF1 = (size_t)BB * SS * DD;            // sub_weights
static constexpr size_t OFF2 = OFF1 + (size_t)BB * SS;          // cat_repr
static constexpr size_t OFF3 = OFF2 + (size_t)BB * CC * DD;     // cat_weights
static constexpr size_t OFF4 = OFF3 + (size_t)BB * CC;          // user_repr

// d_ws layout (floats)
#define WS_ETOT 0      // 400
#define WS_SCE  400    // 285  subcat_embed[s] . w_subcat[:D]
#define WS_SEW  688    // 285  subcat_embed[s] . w_cat[:D]
#define WS_CEDS 976    // 50   clicks_embed[k] . w_subcat[D:]
#define WS_CEDC 1026   // 50   clicks_embed[k] . w_cat[D:]
#define WS_CEW  1076   // 18   cat_embed[c] . w_cat[:D]

typedef float f4 __attribute__((ext_vector_type(4)));
typedef unsigned long long u64;

__device__ __forceinline__ float dot4(f4 a, f4 b) {
    return a.x * b.x + a.y * b.y + a.z * b.z + a.w * b.w;
}

// ---------------------------------------------------------------------------
// Pre-kernel: batch-invariant precomputation into d_ws
// ---------------------------------------------------------------------------
__global__ void hierec_pre(const float* __restrict__ subcat_embed,
                           const float* __restrict__ cat_embed,
                           const float* __restrict__ clicks_embed,
                           const float* __restrict__ w_subcat,
                           const float* __restrict__ w_cat,
                           float* __restrict__ ws)
{
    const int tid  = threadIdx.x;
    const int lane = tid & 63;
    const int wave = tid >> 6;
    const int wpb  = blockDim.x >> 6;
    const int gw   = blockIdx.x * wpb + wave;
    const int nw   = gridDim.x * wpb;

    for (int s = gw; s < SS; s += nw) {
        float p1 = 0.f, p2 = 0.f;
        for (int d = lane; d < DD; d += 64) {
            float v = subcat_embed[s * DD + d];
            p1 += v * w_subcat[d];
            p2 += v * w_cat[d];
        }
        for (int off = 32; off; off >>= 1) {
            p1 += __shfl_down(p1, off);
            p2 += __shfl_down(p2, off);
        }
        if (lane == 0) { ws[WS_SCE + s] = p1; ws[WS_SEW + s] = p2; }
    }
    if (blockIdx.x == 0) {
        for (int d = tid; d < DD; d += blockDim.x) {
            float a = 0.f;
            for (int s = 0; s < SS; ++s) a += subcat_embed[s * DD + d];
            ws[WS_ETOT + d] = a;
        }
    }
    if (blockIdx.x == 1) {
        for (int k = wave; k < HH; k += wpb) {
            float p1 = 0.f, p2 = 0.f;
            if (lane < NCC) {
                float v = clicks_embed[k * NCC + lane];
                p1 = v * w_subcat[DD + lane];
                p2 = v * w_cat[DD + lane];
            }
            for (int off = 32; off; off >>= 1) {
                p1 += __shfl_down(p1, off);
                p2 += __shfl_down(p2, off);
            }
            if (lane == 0) { ws[WS_CEDS + k] = p1; ws[WS_CEDC + k] = p2; }
        }
    }
    if (blockIdx.x == 2) {
        for (int c = wave; c < CC; c += wpb) {
            float p = 0.f;
            for (int d = lane; d < DD; d += 64) p += cat_embed[c * DD + d] * w_cat[d];
            for (int off = 32; off; off >>= 1) p += __shfl_down(p, off);
            if (lane == 0) ws[WS_CEW + c] = p;
        }
    }
}

// ---------------------------------------------------------------------------
// Main fused kernel: one block (256 thr) per batch element, ~16 KB LDS
// ---------------------------------------------------------------------------
__global__ __launch_bounds__(BLOCK, 8) void hierec_main(
    const float* __restrict__ vectors,      // [B,H,D]
    const int*   __restrict__ subcategory,  // [B,H]
    const int*   __restrict__ category,     // [B,H]
    const float* __restrict__ subcat_embed, // [S,D]
    const float* __restrict__ cat_embed,    // [C,D]
    const float* __restrict__ w_news,       // [D]
    const float* __restrict__ w_subcat,     // [D+NC]
    const float* __restrict__ w_cat,        // [D+NC]
    const float* __restrict__ pre,          // d_ws precomputed
    float* __restrict__ out)
{
    const int b    = blockIdx.x;
    const int tid  = threadIdx.x;
    const int lane = tid & 63;
    const int wave = tid >> 6;

    __shared__ f4     vt4L[D4];      // vtot
    __shared__ f4     et4L[D4];      // etot
    __shared__ f4     Wt4L[D4];      // Wtot = sum_h wN[h]*v_h
    __shared__ float  coefS[SS];
    __shared__ u64    maskS[SS];
    __shared__ int    cntS[SS];
    __shared__ float  ns1L[HH], ns2L[HH], ns3L[HH];
    __shared__ float  uzL[HH], wNL[HH], scL[HH], Wn3sL[HH];
    __shared__ u64    maskL[HH];
    __shared__ int    hsL[HH], hcL[HH], repL[HH], prepL[HH];
    __shared__ float  mcL[CC], ucL[CC], rZcL[CC], csL[CC], catwL[CC];
    __shared__ int    cntcL[CC];
    __shared__ int    prepStart[CC + 1];
    __shared__ int    prepHL[HH], prepSL[HH];
    __shared__ float  prepGL[HH];
    __shared__ int    clickedL[HH];
    __shared__ int    unclkL[SS];
    __shared__ int    npL, ndL, nUcnt;
    __shared__ float  PvL, vtwL, etwL, Wn3totL;

    const float* vb  = vectors + (size_t)b * HH * DD;
    const f4*    vb4 = (const f4*)vb;
    const f4*    se4 = (const f4*)subcat_embed;
    const f4*    ce4 = (const f4*)cat_embed;
    f4* o4 = (f4*)(out + (size_t)b * SS * DD);

    // ---------------- P0: ids + inits ----------------
    if (tid < HH) {
        hsL[tid] = subcategory[b * HH + tid];
        hcL[tid] = category[b * HH + tid];
    }
    for (int s = tid; s < SS; s += BLOCK) {
        coefS[s] = 1.f / (float)HH;
        maskS[s] = 0ull;
        cntS[s]  = 0;
    }
    if (tid < D4) {
        et4L[tid] = ((const f4*)pre)[tid];   // WS_ETOT == 0
        f4 z = {0.f, 0.f, 0.f, 0.f};
        vt4L[tid] = z;
        Wt4L[tid] = z;
    }
    if (tid == 0) nUcnt = 0;
    __syncthreads();

    // ---------------- A: single vb pass — 3 dots + vtot partials ----------------
    {
        const f4* wn4 = (const f4*)w_news;
        const f4* ws4 = (const f4*)w_subcat;
        const f4* wc4 = (const f4*)w_cat;
        const bool hi = lane < (D4 - 64);
        f4 vtp0 = {0.f, 0.f, 0.f, 0.f};
        f4 vtp1 = {0.f, 0.f, 0.f, 0.f};
        for (int h = wave; h < HH; h += 4) {
            f4 v0 = vb4[h * D4 + lane];
            float p1 = dot4(v0, wn4[lane]);
            float p2 = dot4(v0, ws4[lane]);
            float p3 = dot4(v0, wc4[lane]);
            vtp0 += v0;
            if (hi) {
                f4 v1 = vb4[h * D4 + 64 + lane];
                p1 += dot4(v1, wn4[64 + lane]);
                p2 += dot4(v1, ws4[64 + lane]);
                p3 += dot4(v1, wc4[64 + lane]);
                vtp1 += v1;
            }
            for (int off = 32; off; off >>= 1) {
                p1 += __shfl_down(p1, off);
                p2 += __shfl_down(p2, off);
                p3 += __shfl_down(p3, off);
            }
            if (lane == 0) { ns1L[h] = p1; ns2L[h] = p2; ns3L[h] = p3; }
        }
        float* vtf = (float*)vt4L;
        atomicAdd(&vtf[4 * lane + 0], vtp0.x);
        atomicAdd(&vtf[4 * lane + 1], vtp0.y);
        atomicAdd(&vtf[4 * lane + 2], vtp0.z);
        atomicAdd(&vtf[4 * lane + 3], vtp0.w);
        if (hi) {
            atomicAdd(&vtf[4 * (64 + lane) + 0], vtp1.x);
            atomicAdd(&vtf[4 * (64 + lane) + 1], vtp1.y);
            atomicAdd(&vtf[4 * (64 + lane) + 2], vtp1.z);
            atomicAdd(&vtf[4 * (64 + lane) + 3], vtp1.w);
        }
    }
    __syncthreads();

    // ---------------- P2: per-click stats (w0) + etw (w1) + vtw (w2) ----------
    if (tid < HH) {
        const int h = tid;
        const int s = hsL[h], c = hcL[h];
        u64 mask = 0ull, pmask = 0ull;
        for (int j = 0; j < HH; ++j) {
            bool ms = (hsL[j] == s);
            mask  |= (u64)(ms ? 1 : 0) << j;
            pmask |= (u64)((ms && hcL[j] == c) ? 1 : 0) << j;
        }
        int cnt = __popcll(mask);
        bool rep = ((__ffsll((long long)mask) - 1) == h);

        float m = FILLV;
        u64 t = mask;
        while (t) { int j = __ffsll((long long)t) - 1; t &= t - 1; m = fmaxf(m, ns1L[j]); }
        float u = expf(FILLV - m);
        float sumE = 0.f, sum2 = 0.f;
        t = mask;
        while (t) {
            int j = __ffsll((long long)t) - 1; t &= t - 1;
            float e = expf(ns1L[j] - m);
            sumE += e;
            sum2 += (e - u) * ns2L[j];
        }
        float Z = sumE + (float)(HH - cnt) * u;
        float vt2 = 0.f;
        for (int j = 0; j < HH; ++j) vt2 += ns2L[j];
        int ci = cnt < (NCC - 1) ? cnt : (NCC - 1);
        float sc = (sum2 + u * vt2) / Z + pre[WS_SCE + s] + pre[WS_CEDS + ci];

        float e_h = expf(ns1L[h] - m);
        float uz = u / Z;
        wNL[h] = (e_h - u) / Z;
        uzL[h] = uz; maskL[h] = mask; scL[h] = sc;
        repL[h]  = rep ? 1 : 0;
        prepL[h] = ((__ffsll((long long)pmask) - 1) == h) ? 1 : 0;
        if (rep) { coefS[s] = uz; maskS[s] = mask; cntS[s] = cnt; }
    } else if (wave == 1) {
        float p = 0.f;
        const float* et = (const float*)et4L;
        for (int d = lane; d < DD; d += 64) p += et[d] * w_cat[d];
        for (int off = 32; off; off >>= 1) p += __shfl_down(p, off);
        if (lane == 0) etwL = p;
    } else if (wave == 2) {
        float p = (lane < HH) ? ns3L[lane] : 0.f;
        for (int off = 32; off; off >>= 1) p += __shfl_down(p, off);
        if (lane == 0) vtwL = p;
    }
    __syncthreads();

    // ---------------- P3a: per-c stats, lists, Wn3s/Wn3tot, small outputs -----
    if (tid < CC) {
        const int c = tid;
        float mc = FILLV; int n = 0, cc2 = 0;
        for (int j = 0; j < HH; ++j) {
            if (hcL[j] == c) ++cc2;
            if (prepL[j] && hcL[j] == c) { ++n; mc = fmaxf(mc, scL[j]); }
        }
        float u = expf(FILLV - mc);
        float sumE = 0.f;
        for (int j = 0; j < HH; ++j)
            if (prepL[j] && hcL[j] == c) sumE += expf(scL[j] - mc);
        float Zc = sumE + (float)(SS - n) * u;
        mcL[c] = mc; ucL[c] = u; rZcL[c] = 1.f / Zc; cntcL[c] = cc2;
        __builtin_nontemporal_store((float)cc2 * (1.f / (float)HH),
                                    &out[OFF3 + (size_t)b * CC + c]);
    } else if (tid == 64) {
        int nd = 0, np = 0;
        float sumUb = 0.f;
        for (int j = 0; j < HH; ++j) {
            if (repL[j]) { clickedL[nd] = hsL[j]; ++nd; sumUb += uzL[j]; }
            if (prepL[j]) ++np;
        }
        npL = np; ndL = nd;
        PvL = (float)(SS - nd) * (1.f / (float)HH) + sumUb;
    } else if (tid >= 128 && tid < 128 + HH) {
        // Wn3s[h] = sum_{j in mask(h)} wN[j]*ns3[j]
        const int h = tid - 128;
        float a = 0.f;
        u64 t = maskL[h];
        while (t) { int j = __ffsll((long long)t) - 1; t &= t - 1; a += wNL[j] * ns3L[j]; }
        Wn3sL[h] = a;
    } else if (wave == 3) {
        const int l = tid - 192;
        float p = (l < HH) ? wNL[l] * ns3L[l] : 0.f;
        for (int off = 32; off; off >>= 1) p += __shfl_down(p, off);
        if (l == 0) Wn3totL = p;
    }
    for (int s = tid; s < SS; s += BLOCK) {
        __builtin_nontemporal_store((float)cntS[s] * (1.f / (float)HH),
                                    &out[OFF1 + (size_t)b * SS + s]);
        if (maskS[s] == 0ull) {
            int p = atomicAdd(&nUcnt, 1);
            unclkL[p] = s;
        }
    }
    __syncthreads();

    // ---------------- P3b: c-sorted prep segments + c_scores (scalar) --------
    if (tid < CC) {
        const int c = tid;
        int start = 0;
        for (int j = 0; j < HH; ++j)
            if (prepL[j] && hcL[j] < c) ++start;
        prepStart[c] = start;
        if (c == 0) prepStart[CC] = npL;
        int cur = start;
        float segs = 0.f;
        for (int j = 0; j < HH; ++j) {
            if (prepL[j] && hcL[j] == c) {
                float g = expf(scL[j] - mcL[c]) - ucL[c];
                prepHL[cur] = j; prepSL[cur] = hsL[j]; prepGL[cur] = g;
                // g * (sub_repr[s] . w_cat)
                segs += g * (uzL[j] * vtwL + Wn3sL[j] + pre[WS_SEW + hsL[j]]);
                ++cur;
            }
        }
        int ci = cntcL[c] < (NCC - 1) ? cntcL[c] : (NCC - 1);
        csL[c] = rZcL[c] * (ucL[c] * (PvL * vtwL + etwL + Wn3totL) + segs)
                 + pre[WS_CEW + c] + pre[WS_CEDC + ci];
    }
    __syncthreads();

    // ---------------- P6b: cat softmax ----------------
    if (tid < CC) {
        float m = csL[0];
        for (int j = 1; j < CC; ++j) m = fmaxf(m, csL[j]);
        float Zc = 0.f;
        for (int j = 0; j < CC; ++j) Zc += expf(csL[j] - m);
        catwL[tid] = expf(csL[tid] - m) / Zc;
    }
    __syncthreads();

    // ---------------- D-clicked: sub_repr clicked rows + Wtot accumulation ----
    {
        const int tot = ndL * D4;
        for (int i = tid; i < tot; i += BLOCK) {
            int ii = i / D4;
            int q  = i - ii * D4;
            int s  = clickedL[ii];
            f4 wsacc = {0.f, 0.f, 0.f, 0.f};
            u64 t = maskS[s];
            while (t) {
                int j = __ffsll((long long)t) - 1; t &= t - 1;
                wsacc += wNL[j] * vb4[j * D4 + q];
            }
            float* wt = (float*)&Wt4L[q];
            atomicAdd(&wt[0], wsacc.x);
            atomicAdd(&wt[1], wsacc.y);
            atomicAdd(&wt[2], wsacc.z);
            atomicAdd(&wt[3], wsacc.w);
            f4 val = coefS[s] * vt4L[q] + wsacc + se4[s * D4 + q];
            o4[s * D4 + q] = val;    // normal store: re-read from L2 in cat phase
        }
    }
    __syncthreads();

    // ======== No more barriers: cat/user (threads<100) overlaps D-fast ========

    // ---------------- C: cat_repr + user_repr from SubTot + L2 row re-reads ---
    if (tid < D4) {
        const int q = tid;
        f4 SubTot = PvL * vt4L[q] + Wt4L[q] + et4L[q];
        f4 uacc = {0.f, 0.f, 0.f, 0.f};
        f4* oc = (f4*)(out + OFF2 + (size_t)b * CC * DD);
        for (int c = 0; c < CC; ++c) {
            f4 acc = ucL[c] * SubTot;
            const int e = prepStart[c + 1];
            for (int jj = prepStart[c]; jj < e; ++jj)
                acc += prepGL[jj] * o4[prepSL[jj] * D4 + q];
            f4 val = rZcL[c] * acc + ce4[c * D4 + q];
            uacc += catwL[c] * val;
            __builtin_nontemporal_store(val, &oc[c * D4 + q]);
        }
        f4* ou = (f4*)(out + OFF4 + (size_t)b * DD);
        __builtin_nontemporal_store(uacc, &ou[q]);
    }

    // ---------------- D-fast: unclicked rows — pure stream ----------------
    {
        const int tot = (SS - ndL) * D4;
        const float cst = 1.f / (float)HH;
        #pragma unroll 4
        for (int i = tid; i < tot; i += BLOCK) {
            int u = i / D4;
            int q = i - u * D4;
            int s = unclkL[u];
            f4 acc = cst * vt4L[q] + se4[s * D4 + q];
            __builtin_nontemporal_store(acc, &o4[s * D4 + q]);
        }
    }
}

extern "C" void kernel_launch(void* const* d_in, const int* in_sizes, int n_in,
                              void* d_out, int out_size, void* d_ws, size_t ws_size,
                              hipStream_t stream) {
    const float* vectors      = (const float*)d_in[0];
    const int*   subcategory  = (const int*)d_in[1];
    const int*   category     = (const int*)d_in[2];
    const float* subcat_embed = (const float*)d_in[3];
    const float* cat_embed    = (const float*)d_in[4];
    const float* clicks_embed = (const float*)d_in[5];
    const float* w_news       = (const float*)d_in[6];
    const float* w_subcat     = (const float*)d_in[7];
    const float* w_cat        = (const float*)d_in[8];
    float* out = (float*)d_out;
    float* ws  = (float*)d_ws;

    hipLaunchKernelGGL(hierec_pre, dim3(32), dim3(256), 0, stream,
                       subcat_embed, cat_embed, clicks_embed, w_subcat, w_cat, ws);
    hipLaunchKernelGGL(hierec_main, dim3(BB), dim3(BLOCK), 0, stream,
                       vectors, subcategory, category, subcat_embed, cat_embed,
                       w_news, w_subcat, w_cat, ws, out);
}